// Round 11
// baseline (184.296 us; speedup 1.0000x reference)
//
#include <hip/hip_runtime.h>
#include <hip/hip_bf16.h>

typedef __hip_bfloat16 bf16;
typedef __attribute__((ext_vector_type(8))) short short8;
typedef __attribute__((ext_vector_type(4))) short sh4;
typedef __attribute__((ext_vector_type(4))) float f32x4;

static __device__ __forceinline__ float bf2f(bf16 h) { return __bfloat162float(h); }
static __device__ __forceinline__ short f2bfs(float f) {
    bf16 h = __float2bfloat16(f);
    return *reinterpret_cast<short*>(&h);
}
static __device__ __forceinline__ short8 cvt8(float4 a, float4 b) {
    short8 o;
    o[0] = f2bfs(a.x); o[1] = f2bfs(a.y); o[2] = f2bfs(a.z); o[3] = f2bfs(a.w);
    o[4] = f2bfs(b.x); o[5] = f2bfs(b.y); o[6] = f2bfs(b.z); o[7] = f2bfs(b.w);
    return o;
}

constexpr int Bn = 8;
constexpr int C  = 256;
constexpr int N  = 1024;     // H*W
constexpr int NH = 8;
constexpr int HD = 32;
constexpr int TS = 264;      // LDS tile stride (shorts)
constexpr float SCALE = 0.17677669529663687f;  // 1/sqrt(32)

// ---------------------------------------------------------------------------
// K1: fused transpose + gates + q/k/v GEMM. 256 threads = 4 waves.
// blocks 0..511: (b, 32-pixel tile, m-half). Stage x^T tile in LDS; wave0
//   computes gumbel gates via one MFMA pair; the 4 waves then compute this
//   block's half of the M=768 (q|k|v) GEMM (mhalf*384 + wave*96, 6 frags),
//   A-frags converted f32->bf16 on the fly, B-frags from the LDS tile.
// blocks 512..515: convert Wp f32 -> Wpb bf16 (for K2).
// 512 work blocks = 2 blocks/CU = 8 waves/CU (R9 was grid-capped at 1).
// ---------------------------------------------------------------------------
__global__ __launch_bounds__(256) void k_fused2(
    const float* __restrict__ x, const float* __restrict__ gq, const float* __restrict__ gk,
    const float* __restrict__ Wsq, const float* __restrict__ bsq,
    const float* __restrict__ Wsk, const float* __restrict__ bsk,
    const float* __restrict__ Wq, const float* __restrict__ bq,
    const float* __restrict__ Wk, const float* __restrict__ bk,
    const float* __restrict__ Wv, const float* __restrict__ bv,
    const float* __restrict__ Wp,
    bf16* __restrict__ qo, bf16* __restrict__ ko, bf16* __restrict__ vo,
    bf16* __restrict__ Wpb, float* __restrict__ sqg)
{
    const int bx  = blockIdx.x;
    const int tid = threadIdx.x;

    if (bx >= 512) {   // Wp convert
        const int seg = bx - 512;
        short* dst = reinterpret_cast<short*>(Wpb);
#pragma unroll
        for (int i = 0; i < 16; ++i) {
            int f4 = seg * 4096 + i * 256 + tid;
            float4 v = reinterpret_cast<const float4*>(Wp)[f4];
            sh4 o;
            o[0] = f2bfs(v.x); o[1] = f2bfs(v.y); o[2] = f2bfs(v.z); o[3] = f2bfs(v.w);
            *reinterpret_cast<sh4*>(dst + (size_t)f4 * 4) = o;
        }
        return;
    }

    __shared__ short T[32 * TS];     // [pixel][c]
    __shared__ float sq_lds[32];
    __shared__ float sk_lds[32];

    const int wave = tid >> 6;
    const int lane = tid & 63;
    const int col  = lane & 15;
    const int quad = lane >> 4;

    const int b     = bx >> 6;
    const int tile  = (bx & 63) >> 1;
    const int mhalf = bx & 1;
    const int n0    = tile * 32;

    // ---- stage x^T tile: 256 c-rows x 32 pixels ----
    {
        const float* xp = x + (size_t)b * C * N + n0;
        const int row = tid >> 3;        // 0..31
        const int f   = tid & 7;         // float4 within 32 pixels
#pragma unroll
        for (int p = 0; p < 8; ++p) {
            int c = p * 32 + row;
            float4 v = *reinterpret_cast<const float4*>(xp + (size_t)c * N + f * 4);
            T[(f * 4 + 0) * TS + c] = f2bfs(v.x);
            T[(f * 4 + 1) * TS + c] = f2bfs(v.y);
            T[(f * 4 + 2) * TS + c] = f2bfs(v.z);
            T[(f * 4 + 3) * TS + c] = f2bfs(v.w);
        }
    }
    __syncthreads();

    // ---- gates (wave 0 only): logits via MFMA, lane-local softmax ----
    if (wave == 0) {
        const float* wsrc = (col < 4) ? (Wsq + col * C) : (Wsk + (col & 3) * C);
        f32x4 ga[2] = {};
#pragma unroll
        for (int k0 = 0; k0 < 256; k0 += 32) {
            float4 w0 = *reinterpret_cast<const float4*>(wsrc + k0 + quad * 8);
            float4 w1 = *reinterpret_cast<const float4*>(wsrc + k0 + quad * 8 + 4);
            short8 af = cvt8(w0, w1);
            short8 b0 = *reinterpret_cast<const short8*>(&T[col * TS + k0 + quad * 8]);
            short8 b1 = *reinterpret_cast<const short8*>(&T[(16 + col) * TS + k0 + quad * 8]);
            ga[0] = __builtin_amdgcn_mfma_f32_16x16x32_bf16(af, b0, ga[0], 0, 0, 0);
            ga[1] = __builtin_amdgcn_mfma_f32_16x16x32_bf16(af, b1, ga[1], 0, 0, 0);
        }
        if (quad < 2) {
            const float* bsrc = (quad == 0) ? bsq : bsk;
            const float* gsrc = (quad == 0) ? gq : gk;
#pragma unroll
            for (int cf = 0; cf < 2; ++cf) {
                int n = n0 + cf * 16 + col;
                float a[4];
#pragma unroll
                for (int r = 0; r < 4; ++r)
                    a[r] = ga[cf][r] + bsrc[r] + gsrc[(size_t)b * 4 * N + (size_t)r * N + n];
                float mx = fmaxf(fmaxf(a[0], a[1]), fmaxf(a[2], a[3]));
                float e = 0.f;
#pragma unroll
                for (int r = 0; r < 4; ++r) e += __expf(a[r] - mx);
                float p0 = __expf(a[0] - mx) / e;
                if (quad == 0) {
                    sq_lds[cf * 16 + col] = p0;
                    if (mhalf == 0) sqg[b * N + n] = p0;
                } else {
                    sk_lds[cf * 16 + col] = p0;
                }
            }
        }
    }
    __syncthreads();

    // ---- this block's GEMM half: M rows [mhalf*384, mhalf*384+384) ----
    const int mbase = mhalf * 384 + wave * 96;
    f32x4 acc[6][2] = {};
#pragma unroll
    for (int k0 = 0; k0 < 256; k0 += 32) {
        short8 b0 = *reinterpret_cast<const short8*>(&T[col * TS + k0 + quad * 8]);
        short8 b1 = *reinterpret_cast<const short8*>(&T[(16 + col) * TS + k0 + quad * 8]);
#pragma unroll
        for (int i = 0; i < 6; ++i) {
            int m = mbase + i * 16;
            const float* wsrc = (m < 256) ? Wq : (m < 512) ? Wk : Wv;
            const float* wr = wsrc + (size_t)((m & 255) + col) * 256 + k0 + quad * 8;
            float4 w0 = *reinterpret_cast<const float4*>(wr);
            float4 w1 = *reinterpret_cast<const float4*>(wr + 4);
            short8 af = cvt8(w0, w1);
            acc[i][0] = __builtin_amdgcn_mfma_f32_16x16x32_bf16(af, b0, acc[i][0], 0, 0, 0);
            acc[i][1] = __builtin_amdgcn_mfma_f32_16x16x32_bf16(af, b1, acc[i][1], 0, 0, 0);
        }
    }
    // epilogue
#pragma unroll
    for (int i = 0; i < 6; ++i) {
        int m = mbase + i * 16;
        int mat = m >> 8;
        int cr  = (m & 255) + quad * 4;
        const float* bb = (mat == 0) ? bq : (mat == 1) ? bk : bv;
        float bias[4];
#pragma unroll
        for (int r = 0; r < 4; ++r) bias[r] = bb[cr + r];
        if (mat < 2) {
            short* op = reinterpret_cast<short*>((mat == 0) ? qo : ko) + (size_t)b * N * C;
#pragma unroll
            for (int cf = 0; cf < 2; ++cf) {
                int n = n0 + cf * 16 + col;
                float g = (mat == 0) ? sq_lds[cf * 16 + col] * SCALE
                                     : sk_lds[cf * 16 + col];
                sh4 pack;
#pragma unroll
                for (int r = 0; r < 4; ++r) pack[r] = f2bfs((acc[i][cf][r] + bias[r]) * g);
                *reinterpret_cast<sh4*>(op + (size_t)n * C + cr) = pack;
            }
        } else {
            bf16* op = vo + (size_t)b * C * N;
#pragma unroll
            for (int cf = 0; cf < 2; ++cf) {
                int n = n0 + cf * 16 + col;
#pragma unroll
                for (int r = 0; r < 4; ++r)
                    op[(size_t)(cr + r) * N + n] = __float2bfloat16(acc[i][cf][r] + bias[r]);
            }
        }
    }
}

// ---------------------------------------------------------------------------
// K2: fused attention + gated mix + projection. 256 threads = 4 waves;
// block = (b, 16-query tile) -> 512 blocks = 2/CU. Wave w handles heads
// {2w, 2w+1} x 16 queries (single Q-frag). Full 256-channel gated row is
// assembled in LDS G (union with P), then the projection GEMM runs
// in-block (each wave: 4 m-frags of Wp).
// ---------------------------------------------------------------------------
union SharedK2 {
    short P[4][16 * 72];    // per-wave [query(16)][key(64)], 9216 B
    short G[16 * TS];       // gated rows [pixel][c], 8448 B
};

__global__ __launch_bounds__(256) void k_attnproj2(
    const bf16* __restrict__ qo, const bf16* __restrict__ ko,
    const bf16* __restrict__ vo, const float* __restrict__ sqg,
    const bf16* __restrict__ Wpb, const float* __restrict__ bp,
    float* __restrict__ out)
{
    __shared__ SharedK2 sh;
    const int tid  = threadIdx.x;
    const int wave = tid >> 6;
    const int lane = tid & 63;
    const int col  = lane & 15;
    const int quad = lane >> 4;

    const int b  = blockIdx.x >> 6;
    const int n0 = (blockIdx.x & 63) * 16;

    const short* qbase   = reinterpret_cast<const short*>(qo) + (size_t)b * N * C;
    const short* kbase_p = reinterpret_cast<const short*>(ko) + (size_t)b * N * C;
    const short* vbase   = reinterpret_cast<const short*>(vo) + (size_t)b * C * N;

    float l[2] = {};
    f32x4 oac[2][2] = {};   // [hh][dh]
    short* P = sh.P[wave];

#pragma unroll
    for (int hh = 0; hh < 2; ++hh) {
        const int h = wave * 2 + hh;
        const short* kp = kbase_p + h * HD + quad * 8;
        const short* vp = vbase + (size_t)h * HD * N;

        short8 qf = *reinterpret_cast<const short8*>(
            qbase + (size_t)(n0 + col) * C + h * HD + quad * 8);

        short8 kf[4];
#pragma unroll
        for (int c = 0; c < 4; ++c)
            kf[c] = *reinterpret_cast<const short8*>(kp + (size_t)(c * 16 + col) * C);

        for (int kb = 0; kb < N; kb += 64) {
            short8 vf[2][2];
#pragma unroll
            for (int kg = 0; kg < 2; ++kg)
#pragma unroll
                for (int dh = 0; dh < 2; ++dh)
                    vf[kg][dh] = *reinterpret_cast<const short8*>(vp + (size_t)(dh * 16 + col) * N + kb + kg * 32 + quad * 8);

            float s[16];
#pragma unroll
            for (int c = 0; c < 4; ++c) {
                f32x4 acc = {};
                acc = __builtin_amdgcn_mfma_f32_16x16x32_bf16(kf[c], qf, acc, 0, 0, 0);
#pragma unroll
                for (int r = 0; r < 4; ++r) s[c * 4 + r] = acc[r];
            }
            float p[16], lloc = 0.f;
#pragma unroll
            for (int i = 0; i < 16; ++i) { p[i] = __expf(s[i]); lloc += p[i]; }
            lloc += __shfl_xor(lloc, 16, 64);
            lloc += __shfl_xor(lloc, 32, 64);
            l[hh] += lloc;
#pragma unroll
            for (int c = 0; c < 4; ++c) {
                sh4 pk;
#pragma unroll
                for (int r = 0; r < 4; ++r) pk[r] = f2bfs(p[c * 4 + r]);
                *reinterpret_cast<sh4*>(&P[col * 72 + c * 16 + quad * 4]) = pk;
            }

            const int kn = (kb + 64) & (N - 1);
#pragma unroll
            for (int c = 0; c < 4; ++c)
                kf[c] = *reinterpret_cast<const short8*>(kp + (size_t)(kn + c * 16 + col) * C);

#pragma unroll
            for (int kg = 0; kg < 2; ++kg) {
                short8 pf = *reinterpret_cast<const short8*>(&P[col * 72 + kg * 32 + quad * 8]);
#pragma unroll
                for (int dh = 0; dh < 2; ++dh)
                    oac[hh][dh] = __builtin_amdgcn_mfma_f32_16x16x32_bf16(vf[kg][dh], pf, oac[hh][dh], 0, 0, 0);
            }
        }
    }

    __syncthreads();   // all waves done with P; safe to overwrite union with G

    // gated mix -> G (each wave fills its 2 heads' 64 channels)
    {
        const int q = n0 + col;
        const float sqv  = sqg[b * N + q];
        const float hv   = 1.f - sqv;
#pragma unroll
        for (int hh = 0; hh < 2; ++hh) {
            const int h = wave * 2 + hh;
            const short* vp = vbase + (size_t)h * HD * N;
            const float invl = 1.f / l[hh];
#pragma unroll
            for (int dh = 0; dh < 2; ++dh) {
                sh4 pack;
#pragma unroll
                for (int r = 0; r < 4; ++r) {
                    int d = dh * 16 + quad * 4 + r;
                    float vb = bf2f(*reinterpret_cast<const bf16*>(vp + (size_t)d * N + q));
                    pack[r] = f2bfs(sqv * (oac[hh][dh][r] * invl) + hv * vb);
                }
                *reinterpret_cast<sh4*>(&sh.G[col * TS + h * HD + dh * 16 + quad * 4]) = pack;
            }
        }
    }

    __syncthreads();

    // projection GEMM: out = Wp @ G + bp; each wave does 4 m-frags (64 rows)
    const short* Wm = reinterpret_cast<const short*>(Wpb);
    f32x4 pacc[4] = {};
#pragma unroll
    for (int k0 = 0; k0 < 256; k0 += 32) {
        short8 b0 = *reinterpret_cast<const short8*>(&sh.G[col * TS + k0 + quad * 8]);
#pragma unroll
        for (int i = 0; i < 4; ++i) {
            short8 af = *reinterpret_cast<const short8*>(Wm + (size_t)(wave * 64 + i * 16 + col) * 256 + k0 + quad * 8);
            pacc[i] = __builtin_amdgcn_mfma_f32_16x16x32_bf16(af, b0, pacc[i], 0, 0, 0);
        }
    }
    float* op = out + (size_t)b * C * N;
#pragma unroll
    for (int i = 0; i < 4; ++i) {
        int cr = wave * 64 + i * 16 + quad * 4;
#pragma unroll
        for (int r = 0; r < 4; ++r)
            op[(size_t)(cr + r) * N + n0 + col] = pacc[i][r] + bp[cr + r];
    }
}

// ---------------------------------------------------------------------------
// Workspace (bytes):
//   [0, 32K)        sqg f32 [8][1024]
//   [32K, 160K)     Wpb bf16 [256][256]
//   [160K, +4M)     qo bf16 [8][1024][256]  (pixel-major, sq*SCALE folded)
//   +4M             ko bf16 [8][1024][256]  (pixel-major, sk folded)
//   +4M             vo bf16 [8][256][1024]  (d-major)
// ---------------------------------------------------------------------------
extern "C" void kernel_launch(void* const* d_in, const int* in_sizes, int n_in,
                              void* d_out, int out_size, void* d_ws, size_t ws_size,
                              hipStream_t stream)
{
    const float* x   = (const float*)d_in[0];
    const float* gq  = (const float*)d_in[1];
    const float* gk  = (const float*)d_in[2];
    const float* Wsq = (const float*)d_in[3];
    const float* bsq = (const float*)d_in[4];
    const float* Wsk = (const float*)d_in[5];
    const float* bsk = (const float*)d_in[6];
    const float* Wq  = (const float*)d_in[7];
    const float* bq  = (const float*)d_in[8];
    const float* Wk  = (const float*)d_in[9];
    const float* bk  = (const float*)d_in[10];
    const float* Wv  = (const float*)d_in[11];
    const float* bv  = (const float*)d_in[12];
    const float* Wp  = (const float*)d_in[13];
    const float* bp  = (const float*)d_in[14];

    char* ws = (char*)d_ws;
    float* sqg = (float*)ws;
    bf16* Wpb  = (bf16*)(ws + 32768);
    bf16* qo   = (bf16*)(ws + 163840);
    bf16* ko   = qo + (size_t)Bn * N * C;
    bf16* vo   = ko + (size_t)Bn * N * C;
    float* out = (float*)d_out;

    k_fused2<<<516, 256, 0, stream>>>(x, gq, gk, Wsq, bsq, Wsk, bsk,
                                      Wq, bq, Wk, bk, Wv, bv, Wp,
                                      qo, ko, vo, Wpb, sqg);
    k_attnproj2<<<512, 256, 0, stream>>>(qo, ko, vo, sqg, Wpb, bp, out);
}

// Round 12
// 165.982 us; speedup vs baseline: 1.1103x; 1.1103x over previous
//
#include <hip/hip_runtime.h>
#include <hip/hip_bf16.h>

typedef __hip_bfloat16 bf16;
typedef __attribute__((ext_vector_type(8))) short short8;
typedef __attribute__((ext_vector_type(4))) short sh4;
typedef __attribute__((ext_vector_type(4))) float f32x4;

static __device__ __forceinline__ float bf2f(bf16 h) { return __bfloat162float(h); }
static __device__ __forceinline__ short f2bfs(float f) {
    bf16 h = __float2bfloat16(f);
    return *reinterpret_cast<short*>(&h);
}
static __device__ __forceinline__ short8 cvt8(float4 a, float4 b) {
    short8 o;
    o[0] = f2bfs(a.x); o[1] = f2bfs(a.y); o[2] = f2bfs(a.z); o[3] = f2bfs(a.w);
    o[4] = f2bfs(b.x); o[5] = f2bfs(b.y); o[6] = f2bfs(b.z); o[7] = f2bfs(b.w);
    return o;
}

constexpr int Bn = 8;
constexpr int C  = 256;
constexpr int N  = 1024;     // H*W
constexpr int NH = 8;
constexpr int HD = 32;
constexpr int TS = 264;      // LDS tile stride (shorts)
constexpr float SCALE = 0.17677669529663687f;  // 1/sqrt(32)

// ---------------------------------------------------------------------------
// K0: convert Wq|Wk|Wv|Wp f32 -> Wb bf16 [4][256][256]. 16 blocks.
// ---------------------------------------------------------------------------
__global__ __launch_bounds__(256) void k_prep(
    const float* __restrict__ Wq, const float* __restrict__ Wk,
    const float* __restrict__ Wv, const float* __restrict__ Wp,
    bf16* __restrict__ Wb)
{
    const int tid = threadIdx.x;
    const int mat = blockIdx.x >> 2, seg = blockIdx.x & 3;
    const float* src = (mat == 0) ? Wq : (mat == 1) ? Wk : (mat == 2) ? Wv : Wp;
    short* dst = reinterpret_cast<short*>(Wb) + (size_t)mat * 256 * 256;
#pragma unroll
    for (int i = 0; i < 16; ++i) {
        int f4 = seg * 4096 + i * 256 + tid;
        float4 v = reinterpret_cast<const float4*>(src)[f4];
        sh4 o;
        o[0] = f2bfs(v.x); o[1] = f2bfs(v.y); o[2] = f2bfs(v.z); o[3] = f2bfs(v.w);
        *reinterpret_cast<sh4*>(dst + (size_t)f4 * 4) = o;
    }
}

// ---------------------------------------------------------------------------
// K1: fused transpose + gates + q/k/v GEMM. 512 blocks = (b, 16-px tile),
// 2 blocks/CU. x read once. Wave computes 12 m-frags (192 rows of M=768)
// with single-b128 A-frags from Wb; B-frag from the LDS x-tile.
// ---------------------------------------------------------------------------
__global__ __launch_bounds__(256) void k_fused3(
    const float* __restrict__ x, const float* __restrict__ gq, const float* __restrict__ gk,
    const float* __restrict__ Wsq, const float* __restrict__ bsq,
    const float* __restrict__ Wsk, const float* __restrict__ bsk,
    const bf16* __restrict__ Wb,
    const float* __restrict__ bq, const float* __restrict__ bk, const float* __restrict__ bv,
    bf16* __restrict__ qo, bf16* __restrict__ ko, bf16* __restrict__ vo,
    float* __restrict__ sqg)
{
    __shared__ short T[16 * TS];     // [pixel][c]
    __shared__ float sq_lds[16];
    __shared__ float sk_lds[16];

    const int tid  = threadIdx.x;
    const int wave = tid >> 6;
    const int lane = tid & 63;
    const int col  = lane & 15;
    const int quad = lane >> 4;

    const int b  = blockIdx.x >> 6;
    const int n0 = (blockIdx.x & 63) * 16;

    // ---- stage x^T tile: 256 c-rows x 16 pixels ----
    {
        const float* xp = x + (size_t)b * C * N + n0;
        const int cr = tid >> 2;         // 0..63
        const int f  = tid & 3;          // float4 within 16 px
#pragma unroll
        for (int p = 0; p < 4; ++p) {
            int c = p * 64 + cr;
            float4 v = *reinterpret_cast<const float4*>(xp + (size_t)c * N + f * 4);
            T[(f * 4 + 0) * TS + c] = f2bfs(v.x);
            T[(f * 4 + 1) * TS + c] = f2bfs(v.y);
            T[(f * 4 + 2) * TS + c] = f2bfs(v.z);
            T[(f * 4 + 3) * TS + c] = f2bfs(v.w);
        }
    }
    __syncthreads();

    // ---- gates (wave 0): logits via one MFMA, lane-local softmax ----
    if (wave == 0) {
        const float* wsrc = (col < 4) ? (Wsq + col * C) : (Wsk + (col & 3) * C);
        f32x4 ga = {};
#pragma unroll
        for (int k0 = 0; k0 < 256; k0 += 32) {
            float4 w0 = *reinterpret_cast<const float4*>(wsrc + k0 + quad * 8);
            float4 w1 = *reinterpret_cast<const float4*>(wsrc + k0 + quad * 8 + 4);
            short8 af = cvt8(w0, w1);
            short8 b0 = *reinterpret_cast<const short8*>(&T[col * TS + k0 + quad * 8]);
            ga = __builtin_amdgcn_mfma_f32_16x16x32_bf16(af, b0, ga, 0, 0, 0);
        }
        if (quad < 2) {
            const float* bsrc = (quad == 0) ? bsq : bsk;
            const float* gsrc = (quad == 0) ? gq : gk;
            int n = n0 + col;
            float a[4];
#pragma unroll
            for (int r = 0; r < 4; ++r)
                a[r] = ga[r] + bsrc[r] + gsrc[(size_t)b * 4 * N + (size_t)r * N + n];
            float mx = fmaxf(fmaxf(a[0], a[1]), fmaxf(a[2], a[3]));
            float e = 0.f;
#pragma unroll
            for (int r = 0; r < 4; ++r) e += __expf(a[r] - mx);
            float p0 = __expf(a[0] - mx) / e;
            if (quad == 0) { sq_lds[col] = p0; sqg[b * N + n] = p0; }
            else            sk_lds[col] = p0;
        }
    }
    __syncthreads();

    // ---- GEMM: 12 m-frags per wave, bf16 A direct b128 ----
    const short* Ws = reinterpret_cast<const short*>(Wb);
    const int mwbase = wave * 192;
    f32x4 acc[12] = {};
#pragma unroll
    for (int k0 = 0; k0 < 256; k0 += 32) {
        short8 b0 = *reinterpret_cast<const short8*>(&T[col * TS + k0 + quad * 8]);
#pragma unroll
        for (int i = 0; i < 12; ++i) {
            int m = mwbase + i * 16;
            const short* wr = Ws + (size_t)(m >> 8) * 65536
                              + (size_t)((m & 255) + col) * 256 + k0 + quad * 8;
            short8 af = *reinterpret_cast<const short8*>(wr);
            acc[i] = __builtin_amdgcn_mfma_f32_16x16x32_bf16(af, b0, acc[i], 0, 0, 0);
        }
    }
    // epilogue
    const int n = n0 + col;
#pragma unroll
    for (int i = 0; i < 12; ++i) {
        int m = mwbase + i * 16;
        int mat = m >> 8;
        int cr  = (m & 255) + quad * 4;
        const float* bb = (mat == 0) ? bq : (mat == 1) ? bk : bv;
        float bias[4];
#pragma unroll
        for (int r = 0; r < 4; ++r) bias[r] = bb[cr + r];
        if (mat < 2) {
            float g = (mat == 0) ? sq_lds[col] * SCALE : sk_lds[col];
            short* op = reinterpret_cast<short*>((mat == 0) ? qo : ko) + (size_t)b * N * C;
            sh4 pack;
#pragma unroll
            for (int r = 0; r < 4; ++r) pack[r] = f2bfs((acc[i][r] + bias[r]) * g);
            *reinterpret_cast<sh4*>(op + (size_t)n * C + cr) = pack;
        } else {
            bf16* op = vo + (size_t)b * C * N;
#pragma unroll
            for (int r = 0; r < 4; ++r)
                op[(size_t)(cr + r) * N + n] = __float2bfloat16(acc[i][r] + bias[r]);
        }
    }
}

// ---------------------------------------------------------------------------
// K2: attention + gated mix. 512 blocks = (b, head, 128-query tile),
// 2 blocks/CU. All 4 waves share one head's K/V stream (L1 reuse); wave =
// 32 queries with 2 Q-frags (1:2 K-load:MFMA). P per-wave LDS (stride 72).
// Writes gated rows to gt [B][N][C] pixel-major.
// ---------------------------------------------------------------------------
__global__ __launch_bounds__(256) void k_attn5(
    const bf16* __restrict__ qo, const bf16* __restrict__ ko,
    const bf16* __restrict__ vo, const float* __restrict__ sqg,
    bf16* __restrict__ gt)
{
    __shared__ short P_lds[4][32 * 72];   // 36.9 KB

    const int tid  = threadIdx.x;
    const int wave = tid >> 6;
    const int lane = tid & 63;
    const int col  = lane & 15;
    const int quad = lane >> 4;

    const int b = blockIdx.x >> 6;
    const int h = (blockIdx.x >> 3) & 7;
    const int qbase = (blockIdx.x & 7) * 128 + wave * 32;

    const short* kp = reinterpret_cast<const short*>(ko) + (size_t)b * N * C + h * HD + quad * 8;
    const short* vp = reinterpret_cast<const short*>(vo) + (size_t)b * C * N + (size_t)h * HD * N;

    short8 qf[2];
    {
        const short* qp = reinterpret_cast<const short*>(qo) + (size_t)b * N * C + h * HD + quad * 8;
#pragma unroll
        for (int g = 0; g < 2; ++g)
            qf[g] = *reinterpret_cast<const short8*>(qp + (size_t)(qbase + g * 16 + col) * C);
    }

    float l[2] = {};
    f32x4 oac[2][2] = {};   // [g][dh]
    short* P = P_lds[wave];

    short8 kf[4];
#pragma unroll
    for (int c = 0; c < 4; ++c)
        kf[c] = *reinterpret_cast<const short8*>(kp + (size_t)(c * 16 + col) * C);

    for (int kb = 0; kb < N; kb += 64) {
        short8 vf[2][2];
#pragma unroll
        for (int kg = 0; kg < 2; ++kg)
#pragma unroll
            for (int dh = 0; dh < 2; ++dh)
                vf[kg][dh] = *reinterpret_cast<const short8*>(vp + (size_t)(dh * 16 + col) * N + kb + kg * 32 + quad * 8);

#pragma unroll
        for (int g = 0; g < 2; ++g) {
            float s[16];
#pragma unroll
            for (int c = 0; c < 4; ++c) {
                f32x4 acc = {};
                acc = __builtin_amdgcn_mfma_f32_16x16x32_bf16(kf[c], qf[g], acc, 0, 0, 0);
#pragma unroll
                for (int r = 0; r < 4; ++r) s[c * 4 + r] = acc[r];
            }
            float p[16], lloc = 0.f;
#pragma unroll
            for (int i = 0; i < 16; ++i) { p[i] = __expf(s[i]); lloc += p[i]; }
            lloc += __shfl_xor(lloc, 16, 64);
            lloc += __shfl_xor(lloc, 32, 64);
            l[g] += lloc;
#pragma unroll
            for (int c = 0; c < 4; ++c) {
                sh4 pk;
#pragma unroll
                for (int r = 0; r < 4; ++r) pk[r] = f2bfs(p[c * 4 + r]);
                *reinterpret_cast<sh4*>(&P[(g * 16 + col) * 72 + c * 16 + quad * 4]) = pk;
            }
        }

        const int kn = (kb + 64) & (N - 1);
#pragma unroll
        for (int c = 0; c < 4; ++c)
            kf[c] = *reinterpret_cast<const short8*>(kp + (size_t)(kn + c * 16 + col) * C);

#pragma unroll
        for (int kg = 0; kg < 2; ++kg) {
#pragma unroll
            for (int g = 0; g < 2; ++g) {
                short8 pf = *reinterpret_cast<const short8*>(&P[(g * 16 + col) * 72 + kg * 32 + quad * 8]);
#pragma unroll
                for (int dh = 0; dh < 2; ++dh)
                    oac[g][dh] = __builtin_amdgcn_mfma_f32_16x16x32_bf16(vf[kg][dh], pf, oac[g][dh], 0, 0, 0);
            }
        }
    }

    // epilogue: gated mix, pixel-major packed stores
#pragma unroll
    for (int g = 0; g < 2; ++g) {
        const int q = qbase + g * 16 + col;
        const float invl = 1.f / l[g];
        const float sqv  = sqg[b * N + q];
        const float hv   = 1.f - sqv;
        short* gp = reinterpret_cast<short*>(gt) + ((size_t)b * N + q) * C + h * HD + quad * 4;
#pragma unroll
        for (int dh = 0; dh < 2; ++dh) {
            sh4 pack;
#pragma unroll
            for (int r = 0; r < 4; ++r) {
                int d = dh * 16 + quad * 4 + r;
                float vb = bf2f(*reinterpret_cast<const bf16*>(vp + (size_t)d * N + q));
                pack[r] = f2bfs(sqv * (oac[g][dh][r] * invl) + hv * vb);
            }
            *reinterpret_cast<sh4*>(gp + dh * 16) = pack;
        }
    }
}

// ---------------------------------------------------------------------------
// K3: projection MFMA GEMM (R6-proven). grid (4, 32, 8) = 1024 blocks.
// out = Wp @ g + bp, f32 [B][C][N].
// ---------------------------------------------------------------------------
__global__ __launch_bounds__(256) void k_projm2(
    const bf16* __restrict__ gt, const bf16* __restrict__ Wpb,
    const float* __restrict__ bp, float* __restrict__ out)
{
    const int tid  = threadIdx.x;
    const int wave = tid >> 6, lane = tid & 63;
    const int col  = lane & 15, quad = lane >> 4;
    const int mrow = blockIdx.x * 64;
    const int b    = blockIdx.z;
    const int n0   = blockIdx.y * 32;

    const short* Wm = reinterpret_cast<const short*>(Wpb);
    const short* gp = reinterpret_cast<const short*>(gt) + (size_t)b * N * C;
    const int m16 = mrow + wave * 16;

    f32x4 acc[2] = {};
#pragma unroll
    for (int k0 = 0; k0 < 256; k0 += 32) {
        short8 af = *reinterpret_cast<const short8*>(Wm + (size_t)(m16 + col) * 256 + k0 + quad * 8);
#pragma unroll
        for (int cf = 0; cf < 2; ++cf) {
            short8 bfr = *reinterpret_cast<const short8*>(gp + (size_t)(n0 + cf * 16 + col) * C + k0 + quad * 8);
            acc[cf] = __builtin_amdgcn_mfma_f32_16x16x32_bf16(af, bfr, acc[cf], 0, 0, 0);
        }
    }

    float bias[4];
#pragma unroll
    for (int r = 0; r < 4; ++r) bias[r] = bp[m16 + quad * 4 + r];
    float* op = out + (size_t)b * C * N;
#pragma unroll
    for (int cf = 0; cf < 2; ++cf) {
        int n = n0 + cf * 16 + col;
#pragma unroll
        for (int r = 0; r < 4; ++r) {
            int c = m16 + quad * 4 + r;
            op[(size_t)c * N + n] = acc[cf][r] + bias[r];
        }
    }
}

// ---------------------------------------------------------------------------
// Workspace (bytes):
//   [0, 32K)        sqg f32 [8][1024]
//   [32K, 544K)     Wb bf16 [4][256][256]  (q,k,v,p)
//   [544K, +4M)     qo bf16 [8][1024][256] (pixel-major, sq*SCALE folded)
//   +4M             ko bf16 [8][1024][256] (pixel-major, sk folded)
//   +4M             vo bf16 [8][256][1024] (d-major)
//   +4M             gt bf16 [8][1024][256] (gated rows, pixel-major)
// ---------------------------------------------------------------------------
extern "C" void kernel_launch(void* const* d_in, const int* in_sizes, int n_in,
                              void* d_out, int out_size, void* d_ws, size_t ws_size,
                              hipStream_t stream)
{
    const float* x   = (const float*)d_in[0];
    const float* gq  = (const float*)d_in[1];
    const float* gk  = (const float*)d_in[2];
    const float* Wsq = (const float*)d_in[3];
    const float* bsq = (const float*)d_in[4];
    const float* Wsk = (const float*)d_in[5];
    const float* bsk = (const float*)d_in[6];
    const float* Wq  = (const float*)d_in[7];
    const float* bq  = (const float*)d_in[8];
    const float* Wk  = (const float*)d_in[9];
    const float* bk  = (const float*)d_in[10];
    const float* Wv  = (const float*)d_in[11];
    const float* bv  = (const float*)d_in[12];
    const float* Wp  = (const float*)d_in[13];
    const float* bp  = (const float*)d_in[14];

    char* ws = (char*)d_ws;
    float* sqg = (float*)ws;
    bf16* Wb   = (bf16*)(ws + 32768);
    bf16* qo   = (bf16*)(ws + 32768 + 524288);
    bf16* ko   = qo + (size_t)Bn * N * C;
    bf16* vo   = ko + (size_t)Bn * N * C;
    bf16* gt   = vo + (size_t)Bn * C * N;
    float* out = (float*)d_out;

    k_prep<<<16, 256, 0, stream>>>(Wq, Wk, Wv, Wp, Wb);
    k_fused3<<<512, 256, 0, stream>>>(x, gq, gk, Wsq, bsq, Wsk, bsk,
                                      Wb, bq, bk, bv, qo, ko, vo, sqg);
    k_attn5<<<512, 256, 0, stream>>>(qo, ko, vo, sqg, gt);
    k_projm2<<<dim3(4, 32, 8), 256, 0, stream>>>(gt, Wb + 3 * 65536, bp, out);
}